// Round 3
// baseline (118.865 us; speedup 1.0000x reference)
//
#include <hip/hip_runtime.h>
#include <math.h>

#define NB      8192
#define HLEN    200
#define DIM     128
#define AH      64
#define NITEMS  100000
#define NTILE   13

typedef __attribute__((ext_vector_type(4))) float f32x4;
typedef __attribute__((ext_vector_type(2))) float f32x2;
typedef __attribute__((ext_vector_type(4))) int   i32x4;
typedef __attribute__((ext_vector_type(8))) short bf16x8;
typedef unsigned int uint;

__device__ __forceinline__ unsigned short f2bf(float f) {
  uint u = __float_as_uint(f);
  u += 0x7fffu + ((u >> 16) & 1u);
  return (unsigned short)(u >> 16);
}
__device__ __forceinline__ float bf2f(unsigned short h) {
  return __uint_as_float(((uint)h) << 16);
}

// fp4 e2m1 (x0.5 global scale) magnitude -> fp8 e4m3 byte LUT via v_perm_b32.
// mag 0..7 -> {0.0,0.25,0.5,0.75,1.0,1.5,2.0,3.0} = {00,28,30,34,38,3C,40,44}
__device__ __forceinline__ uint permlut(uint sel) {
  uint d;
  asm("v_perm_b32 %0, %1, %2, %3" : "=v"(d)
      : "v"(0x44403C38u), "v"(0x34302800u), "v"(sel));
  return d;
}
// w: 8 fp4 nibbles (cols base..base+7, even cols in low nibbles).
// pe: fp8 bytes of cols {base,base+2,base+4,base+6}; po: odd cols.
__device__ __forceinline__ void dec8(uint w, uint& pe, uint& po) {
  uint mlo = w & 0x07070707u;
  uint mhi = (w >> 4) & 0x07070707u;
  uint slo = (w & 0x08080808u) << 4;
  uint shi = w & 0x80808080u;
  pe = permlut(mlo) | slo;
  po = permlut(mhi) | shi;
}
// encode one float to fp4 nibble (value grid = 0.5*e2m1, round-to-nearest)
__device__ __forceinline__ uint encf4(float v) {
  float a = fabsf(v) * 2.0f;
  uint n = 0;
  n += (a >= 0.25f); n += (a >= 0.75f); n += (a >= 1.25f); n += (a >= 1.75f);
  n += (a >= 2.5f);  n += (a >= 3.5f);  n += (a >= 5.0f);
  return n | ((__float_as_uint(v) >> 28) & 8u);
}

// ---------------------------------------------------------------------------
// Pre-kernel: blocks [0,256) = bilinear interaction + item_emb copy;
// blocks [256,1280) = item_table f32 -> fp4 + w1 -> fp8 MFMA-layout table.
// w1f8[(((part*4+s)*4+nt)*16+m)*4+g)*8+j] = fp8(w1[part*128 + g*32 + s*8 +
//   ((j&3)*2 + (j>>2))][nt*16+m])
// ---------------------------------------------------------------------------
#define INTER_BLKS (NB / 32)
__global__ __launch_bounds__(256)
void pre_kernel(const int* __restrict__ user_ids,
                const int* __restrict__ item_ids,
                const float* __restrict__ user_table,
                const float* __restrict__ item_table,
                const float* __restrict__ fi,
                const float* __restrict__ w1,
                unsigned char* __restrict__ tbl4,
                unsigned char* __restrict__ w1f8,
                float* __restrict__ out_item,
                float* __restrict__ out_inter) {
  const int t = threadIdx.x;
  if (blockIdx.x < INTER_BLKS) {
    // ---------------- bilinear interaction (verified r1/r2 body) ----------
    __shared__ unsigned short fitb[DIM * 130];
    __shared__ float u4[4][DIM];
    __shared__ float red[4][4];
    for (int i = t; i < DIM * DIM; i += 256) {
      int d = i >> 7, e = i & 127;
      fitb[e * 130 + d] = f2bf(fi[i]);
    }
    const int col = t & 127;
    const int dh = t >> 7;
    const int lane = t & 63;
    const int wv = t >> 6;
    const int b0 = blockIdx.x * 32;
    const unsigned short* fr = &fitb[col * 130 + dh * 64];
    for (int grp = 0; grp < 8; ++grp) {
      __syncthreads();
      for (int i = t; i < 4 * DIM; i += 256) {
        int bi = i >> 7, d = i & 127;
        u4[bi][d] = user_table[(long)user_ids[b0 + grp * 4 + bi] * DIM + d];
      }
      __syncthreads();
      float a0 = 0.f, a1 = 0.f, a2 = 0.f, a3 = 0.f;
#pragma unroll 4
      for (int d = 0; d < 64; d += 4) {
        float f0 = bf2f(fr[d]), f1 = bf2f(fr[d + 1]), f2 = bf2f(fr[d + 2]), f3 = bf2f(fr[d + 3]);
        f32x4 q0 = *(const f32x4*)&u4[0][dh * 64 + d];
        f32x4 q1 = *(const f32x4*)&u4[1][dh * 64 + d];
        f32x4 q2 = *(const f32x4*)&u4[2][dh * 64 + d];
        f32x4 q3 = *(const f32x4*)&u4[3][dh * 64 + d];
        a0 = fmaf(f0, q0[0], a0); a0 = fmaf(f1, q0[1], a0); a0 = fmaf(f2, q0[2], a0); a0 = fmaf(f3, q0[3], a0);
        a1 = fmaf(f0, q1[0], a1); a1 = fmaf(f1, q1[1], a1); a1 = fmaf(f2, q1[2], a1); a1 = fmaf(f3, q1[3], a1);
        a2 = fmaf(f0, q2[0], a2); a2 = fmaf(f1, q2[1], a2); a2 = fmaf(f2, q2[2], a2); a2 = fmaf(f3, q2[3], a2);
        a3 = fmaf(f0, q3[0], a3); a3 = fmaf(f1, q3[1], a3); a3 = fmaf(f2, q3[2], a3); a3 = fmaf(f3, q3[3], a3);
      }
      const int bb = b0 + grp * 4;
      const float vv0 = item_table[(long)item_ids[bb + 0] * DIM + col];
      const float vv1 = item_table[(long)item_ids[bb + 1] * DIM + col];
      const float vv2 = item_table[(long)item_ids[bb + 2] * DIM + col];
      const float vv3 = item_table[(long)item_ids[bb + 3] * DIM + col];
      if (dh == 0) {
        out_item[(long)(bb + 0) * DIM + col] = vv0;
        out_item[(long)(bb + 1) * DIM + col] = vv1;
        out_item[(long)(bb + 2) * DIM + col] = vv2;
        out_item[(long)(bb + 3) * DIM + col] = vv3;
      }
      float p0 = a0 * vv0, p1 = a1 * vv1, p2 = a2 * vv2, p3 = a3 * vv3;
#pragma unroll
      for (int msk = 1; msk <= 32; msk <<= 1) {
        p0 += __shfl_xor(p0, msk);
        p1 += __shfl_xor(p1, msk);
        p2 += __shfl_xor(p2, msk);
        p3 += __shfl_xor(p3, msk);
      }
      if (lane == 0) { red[wv][0] = p0; red[wv][1] = p1; red[wv][2] = p2; red[wv][3] = p3; }
      __syncthreads();
      if (t < 4)
        out_inter[bb + t] = red[0][t] + red[1][t] + red[2][t] + red[3][t];
    }
  } else {
    // ---------------- converters ------------------------------------------
    const int cb = blockIdx.x - INTER_BLKS;
    const int cgrid = gridDim.x - INTER_BLKS;
    const long t0 = (long)cb * 256 + t;
    const long total = (long)NITEMS * DIM / 8;   // one u32 per 8 cols
    const long stride = (long)cgrid * 256;
    for (long o = t0; o < total; o += stride) {
      const float* p = item_table + o * 8;
      f32x4 x0 = *(const f32x4*)p;
      f32x4 x1 = *(const f32x4*)(p + 4);
      uint w = 0;
      w |= encf4(x0[0]);       w |= encf4(x0[1]) << 4;
      w |= encf4(x0[2]) << 8;  w |= encf4(x0[3]) << 12;
      w |= encf4(x1[0]) << 16; w |= encf4(x1[1]) << 20;
      w |= encf4(x1[2]) << 24; w |= encf4(x1[3]) << 28;
      ((uint*)tbl4)[o] = w;
    }
    if (t0 < 16384) {
      int L = (int)t0;
      int j = L & 7, g = (L >> 3) & 3, m = (L >> 5) & 15;
      int nt = (L >> 9) & 3, s = (L >> 11) & 3, part = (L >> 13) & 1;
      int kg = part * 128 + g * 32 + s * 8 + (j & 3) * 2 + (j >> 2);
      float v = w1[kg * AH + nt * 16 + m];
      int pk = __builtin_amdgcn_cvt_pk_fp8_f32(v, v, 0, false);
      w1f8[L] = (unsigned char)(pk & 0xff);
    }
  }
}

// ---------------------------------------------------------------------------
// Main kernel: fused attention pooling over fp4 rows. One wave per batch
// element; ONE dwordx4 gather per 16-row tile; fp8 MFMA for scores.
// ---------------------------------------------------------------------------
__global__ __launch_bounds__(256, 4)
void main_kernel_fp4(const int* __restrict__ user_ids,
                     const int* __restrict__ user_history,
                     const float* __restrict__ user_table,
                     const unsigned char* __restrict__ tbl4,
                     const unsigned char* __restrict__ w1f8,
                     const float* __restrict__ b1,
                     const float* __restrict__ w2,
                     const float* __restrict__ b2,
                     float* __restrict__ out_user) {
  const int lane = threadIdx.x & 63;
  const int wave = threadIdx.x >> 6;
  const int b = blockIdx.x * 4 + wave;
  const int m = lane & 15;
  const int g = lane >> 4;

  const int uid = __builtin_amdgcn_readfirstlane(user_ids[b]);
  const float* urow = user_table + (long)uid * DIM;
  const int* hrow = user_history + (long)b * HLEN;

  int idxs[NTILE];
#pragma unroll
  for (int t = 0; t < NTILE; ++t) {
    int row = t * 16 + m;
    idxs[t] = (row < HLEN) ? hrow[row] : 0;
  }

  // ---- u -> fp8 A-fragments in the permuted k-order ----
  int ufd[8];
#pragma unroll
  for (int s = 0; s < 4; ++s) {
    const float* up = urow + g * 32 + s * 8;
    int e = __builtin_amdgcn_cvt_pk_fp8_f32(up[0], up[2], 0, false);
    e     = __builtin_amdgcn_cvt_pk_fp8_f32(up[4], up[6], e, true);
    int o = __builtin_amdgcn_cvt_pk_fp8_f32(up[1], up[3], 0, false);
    o     = __builtin_amdgcn_cvt_pk_fp8_f32(up[5], up[7], o, true);
    ufd[2 * s] = e; ufd[2 * s + 1] = o;
  }

  const unsigned char* wtop = w1f8;
  const unsigned char* wbot = w1f8 + 8192;

  // ---- u-projection via MFMA ----
  f32x4 accu[4];
#pragma unroll
  for (int nt = 0; nt < 4; ++nt) accu[nt] = (f32x4){0.f, 0.f, 0.f, 0.f};
#pragma unroll
  for (int s = 0; s < 4; ++s) {
    long a_s = (long)(uint)ufd[2 * s] | ((long)(uint)ufd[2 * s + 1] << 32);
#pragma unroll
    for (int nt = 0; nt < 4; ++nt) {
      long bf = *(const long*)(wtop + (((s * 4 + nt) * 16 + m) * 4 + g) * 8);
      accu[nt] = __builtin_amdgcn_mfma_f32_16x16x32_fp8_fp8(a_s, bf, accu[nt], 0, 0, 0);
    }
  }
  float ubreg[4], w2reg[4];
#pragma unroll
  for (int nt = 0; nt < 4; ++nt) {
    ubreg[nt] = accu[nt][0] + b1[nt * 16 + m];
    w2reg[nt] = w2[nt * 16 + m];
  }
  const float b2v = b2[0];

  long bfr[4][4];
#pragma unroll
  for (int s = 0; s < 4; ++s)
#pragma unroll
    for (int nt = 0; nt < 4; ++nt)
      bfr[s][nt] = *(const long*)(wbot + (((s * 4 + nt) * 16 + m) * 4 + g) * 8);

  float arep[32];
#pragma unroll
  for (int c = 0; c < 32; ++c) arep[c] = 0.f;

  // ---- depth-3 pipelined main loop: 1 gather instruction per tile ----
  i32x4 pa[3];
#define LOADT(T, BUF) pa[BUF] = *(const i32x4*)(tbl4 + ((long)idxs[T] << 6) + g * 16);
  LOADT(0, 0)
  LOADT(1, 1)
#pragma unroll
  for (int t = 0; t < NTILE; ++t) {
    if (t + 2 < NTILE) LOADT(t + 2, (t + 2) % 3)
    const int cb = t % 3;

    // decode fp4 -> fp8 (8 dwords, permuted col order baked into w1f8)
    uint p8[8];
#pragma unroll
    for (int i = 0; i < 4; ++i) {
      uint pe, po;
      dec8((uint)pa[cb][i], pe, po);
      p8[2 * i] = pe; p8[2 * i + 1] = po;
    }

    f32x4 acc[4];
#pragma unroll
    for (int nt = 0; nt < 4; ++nt) acc[nt] = (f32x4){0.f, 0.f, 0.f, 0.f};
#pragma unroll
    for (int s = 0; s < 4; ++s) {
      long a_s = (long)p8[2 * s] | ((long)p8[2 * s + 1] << 32);
#pragma unroll
      for (int nt = 0; nt < 4; ++nt)
        acc[nt] = __builtin_amdgcn_mfma_f32_16x16x32_fp8_fp8(a_s, bfr[s][nt], acc[nt], 0, 0, 0);
    }

    float sums[4];
#pragma unroll
    for (int r = 0; r < 4; ++r) {
      float s = 0.f;
#pragma unroll
      for (int nt = 0; nt < 4; ++nt) {
        float h = fmaxf(acc[nt][r] + ubreg[nt], 0.f);
        s = fmaf(h, w2reg[nt], s);
      }
      s += __shfl_xor(s, 1);
      s += __shfl_xor(s, 2);
      s += __shfl_xor(s, 4);
      s += __shfl_xor(s, 8);
      sums[r] = s;
    }
    const int q = m & 3;
    float keep = (q == 0) ? sums[0] : (q == 1) ? sums[1] : (q == 2) ? sums[2] : sums[3];
    float sv = __shfl(keep, ((m >> 2) << 4) | m);
    float attw = 1.f / (1.f + __expf(-(sv + b2v)));
    if (t * 16 + m >= HLEN) attw = 0.f;

    // weighted accumulate: fp8 -> f32 decode of the same registers
#pragma unroll
    for (int i = 0; i < 8; ++i) {
      f32x2 lo = __builtin_amdgcn_cvt_pk_f32_fp8(p8[i], false);
      f32x2 hi = __builtin_amdgcn_cvt_pk_f32_fp8(p8[i], true);
      const int base = i * 4;
      arep[base + 0] = fmaf(attw, lo[0], arep[base + 0]);
      arep[base + 1] = fmaf(attw, lo[1], arep[base + 1]);
      arep[base + 2] = fmaf(attw, hi[0], arep[base + 2]);
      arep[base + 3] = fmaf(attw, hi[1], arep[base + 3]);
    }
  }
#undef LOADT

#pragma unroll
  for (int c = 0; c < 32; ++c) {
    arep[c] += __shfl_xor(arep[c], 1);
    arep[c] += __shfl_xor(arep[c], 2);
    arep[c] += __shfl_xor(arep[c], 4);
    arep[c] += __shfl_xor(arep[c], 8);
  }
  if (m == 0) {
    // register order within each dword-pair i: cols base + {0,2,4,6,1,3,5,7}
#pragma unroll
    for (int i = 0; i < 4; ++i) {
      const int colb = g * 32 + i * 8;
      const float* ar = &arep[i * 8];
      f32x4 u0 = *(const f32x4*)(urow + colb);
      f32x4 u1 = *(const f32x4*)(urow + colb + 4);
      f32x4 o0, o1;
      o0[0] = u0[0] + ar[0]; o0[1] = u0[1] + ar[4];
      o0[2] = u0[2] + ar[1]; o0[3] = u0[3] + ar[5];
      o1[0] = u1[0] + ar[2]; o1[1] = u1[1] + ar[6];
      o1[2] = u1[2] + ar[3]; o1[3] = u1[3] + ar[7];
      *(f32x4*)(out_user + (long)b * DIM + colb) = o0;
      *(f32x4*)(out_user + (long)b * DIM + colb + 4) = o1;
    }
  }
}

// ---------------------------------------------------------------------------
// Fallback (ws too small): f32 table reads + inline bf16 (r1, verified).
// ---------------------------------------------------------------------------
__global__ __launch_bounds__(256)
void main_fallback(const int* __restrict__ user_ids,
                   const int* __restrict__ user_history,
                   const float* __restrict__ user_table,
                   const float* __restrict__ item_table,
                   const float* __restrict__ w1,
                   const float* __restrict__ b1,
                   const float* __restrict__ w2,
                   const float* __restrict__ b2,
                   float* __restrict__ out_user) {
  const int lane = threadIdx.x & 63;
  const int wave = threadIdx.x >> 6;
  const int b = blockIdx.x * 4 + wave;
  const int m = lane & 15, g = lane >> 4;
  const int uid = __builtin_amdgcn_readfirstlane(user_ids[b]);
  const float* urow = user_table + (long)uid * DIM;
  float upj = b1[lane];
#pragma unroll 8
  for (int d = 0; d < DIM; ++d) upj = fmaf(urow[d], w1[d * AH + lane], upj);
  bf16x8 bfr[4][4];
#pragma unroll
  for (int ks = 0; ks < 4; ++ks)
#pragma unroll
    for (int nt = 0; nt < 4; ++nt) {
      bf16x8 bv;
#pragma unroll
      for (int j = 0; j < 8; ++j)
        bv[j] = (short)f2bf(w1[(DIM + ks * 32 + g * 8 + j) * AH + nt * 16 + m]);
      bfr[ks][nt] = bv;
    }
  float ubreg[4], w2reg[4];
#pragma unroll
  for (int nt = 0; nt < 4; ++nt) {
    ubreg[nt] = __shfl(upj, nt * 16 + m);
    w2reg[nt] = w2[nt * 16 + m];
  }
  const float b2v = b2[0];
  float arep[32];
#pragma unroll
  for (int c = 0; c < 32; ++c) arep[c] = 0.f;
  const int* hrow = user_history + (long)b * HLEN;
  for (int t = 0; t < NTILE; ++t) {
    const int row = t * 16 + m;
    const int idx = (row < HLEN) ? hrow[row] : 0;
    bf16x8 a[4];
    const float* rp = item_table + (long)idx * DIM;
#pragma unroll
    for (int ks = 0; ks < 4; ++ks) {
      f32x4 lo = *(const f32x4*)(rp + ks * 32 + g * 8);
      f32x4 hi = *(const f32x4*)(rp + ks * 32 + g * 8 + 4);
      bf16x8 av;
      av[0] = (short)f2bf(lo[0]); av[1] = (short)f2bf(lo[1]);
      av[2] = (short)f2bf(lo[2]); av[3] = (short)f2bf(lo[3]);
      av[4] = (short)f2bf(hi[0]); av[5] = (short)f2bf(hi[1]);
      av[6] = (short)f2bf(hi[2]); av[7] = (short)f2bf(hi[3]);
      a[ks] = av;
    }
    f32x4 acc[4];
#pragma unroll
    for (int nt = 0; nt < 4; ++nt) acc[nt] = (f32x4){0.f, 0.f, 0.f, 0.f};
#pragma unroll
    for (int ks = 0; ks < 4; ++ks)
#pragma unroll
      for (int nt = 0; nt < 4; ++nt)
        acc[nt] = __builtin_amdgcn_mfma_f32_16x16x32_bf16(a[ks], bfr[ks][nt], acc[nt], 0, 0, 0);
    float sums[4];
#pragma unroll
    for (int r = 0; r < 4; ++r) {
      float s = 0.f;
#pragma unroll
      for (int nt = 0; nt < 4; ++nt) {
        float h = fmaxf(acc[nt][r] + ubreg[nt], 0.f);
        s = fmaf(h, w2reg[nt], s);
      }
      s += __shfl_xor(s, 1); s += __shfl_xor(s, 2);
      s += __shfl_xor(s, 4); s += __shfl_xor(s, 8);
      sums[r] = s;
    }
    const int q = m & 3;
    float keep = (q == 0) ? sums[0] : (q == 1) ? sums[1] : (q == 2) ? sums[2] : sums[3];
    float sv = __shfl(keep, ((m >> 2) << 4) | m);
    float attw = 1.f / (1.f + __expf(-(sv + b2v)));
    if (row >= HLEN) attw = 0.f;
#pragma unroll
    for (int ks = 0; ks < 4; ++ks)
#pragma unroll
      for (int j = 0; j < 8; ++j)
        arep[ks * 8 + j] = fmaf(attw, bf2f((unsigned short)a[ks][j]), arep[ks * 8 + j]);
  }
#pragma unroll
  for (int c = 0; c < 32; ++c) {
    arep[c] += __shfl_xor(arep[c], 1);
    arep[c] += __shfl_xor(arep[c], 2);
    arep[c] += __shfl_xor(arep[c], 4);
    arep[c] += __shfl_xor(arep[c], 8);
  }
  if (m == 0) {
#pragma unroll
    for (int ks = 0; ks < 4; ++ks)
#pragma unroll
      for (int j = 0; j < 8; ++j) {
        const int col = ks * 32 + g * 8 + j;
        out_user[(long)b * DIM + col] = urow[col] + arep[ks * 8 + j];
      }
  }
}

// ---------------------------------------------------------------------------
extern "C" void kernel_launch(void* const* d_in, const int* in_sizes, int n_in,
                              void* d_out, int out_size, void* d_ws, size_t ws_size,
                              hipStream_t stream) {
  const int*   user_ids     = (const int*)d_in[0];
  const int*   item_ids     = (const int*)d_in[1];
  const int*   user_history = (const int*)d_in[2];
  const float* user_table   = (const float*)d_in[3];
  const float* item_table   = (const float*)d_in[4];
  const float* fi           = (const float*)d_in[5];
  const float* w1           = (const float*)d_in[6];
  const float* b1           = (const float*)d_in[7];
  const float* w2           = (const float*)d_in[8];
  const float* b2           = (const float*)d_in[9];

  float* out       = (float*)d_out;
  float* out_user  = out;
  float* out_item  = out + (size_t)NB * DIM;
  float* out_inter = out + (size_t)2 * NB * DIM;

  const size_t tbl4_bytes = (size_t)NITEMS * DIM / 2;   // 6.4 MB
  const size_t need = tbl4_bytes + 16384;
  if (ws_size >= need) {
    unsigned char* tbl4 = (unsigned char*)d_ws;
    unsigned char* w1f8 = tbl4 + tbl4_bytes;
    pre_kernel<<<INTER_BLKS + 1024, 256, 0, stream>>>(user_ids, item_ids, user_table,
        item_table, fi, w1, tbl4, w1f8, out_item, out_inter);
    main_kernel_fp4<<<NB / 4, 256, 0, stream>>>(user_ids, user_history, user_table,
        tbl4, w1f8, b1, w2, b2, out_user);
  } else {
    main_fallback<<<NB / 4, 256, 0, stream>>>(user_ids, user_history, user_table,
        item_table, w1, b1, w2, b2, out_user);
    // inter via pre_kernel's inter blocks only
    pre_kernel<<<INTER_BLKS, 256, 0, stream>>>(user_ids, item_ids, user_table,
        item_table, fi, w1, nullptr, nullptr, out_item, out_inter);
  }
}